// Round 18
// baseline (126.089 us; speedup 1.0000x reference)
//
#include <hip/hip_runtime.h>
#include <math.h>

// Problem constants: B=1, C=64, D=H=W=16, HEADS=4, HD=16
#define CN   262144        // C * 4096 floats per [C, D, H, W] tensor
#define BTP 196            // qkv/conv Bt row stride in bf16

typedef __attribute__((ext_vector_type(8))) short short8;   // 8 bf16 (4 VGPRs)
typedef __attribute__((ext_vector_type(4))) short short4v;  // 8 B
typedef __attribute__((ext_vector_type(4))) float float4v;  // MFMA C/D

static __device__ __forceinline__ unsigned short f2bf(float f) {
    union { float f; unsigned u; } v; v.f = f;
    unsigned r = (v.u + 0x7FFFu + ((v.u >> 16) & 1u)) >> 16;   // RNE
    return (unsigned short)r;
}

// ---------------------------------------------------------------------------
// Dispatch 1: spatial conv 3x3 as MFMA GEMM (blocks 0..255) + wfuse (256..399).
// (r17-verified, unchanged.)
__global__ __launch_bounds__(256, 4) void conv_sp_wfuse_kernel(
        const float* __restrict__ x, const float* __restrict__ w_sp,
        const float* __restrict__ b_sp, float* __restrict__ y1,
        const float* __restrict__ w_spec, const float* __restrict__ b_spec,
        const float* __restrict__ w_qkv, const float* __restrict__ b_qkv,
        unsigned short* __restrict__ wfb, float* __restrict__ bfv) {
    int tid = threadIdx.x;               // 256
    if (blockIdx.x >= 256) {
        int idx = (blockIdx.x - 256) * 256 + tid;    // 0..36863
        int oc = idx / 192;
        int r  = idx % 192;                          // = cj*3 + t
        float s = 0.f;
        #pragma unroll 8
        for (int ci = 0; ci < 64; ++ci)
            s += w_qkv[oc * 64 + ci] * w_spec[ci * 192 + r];
        if (oc < 64) s *= 0.25f;
        wfb[oc * 192 + r] = f2bf(s);
        if (idx < 192) {
            float t = b_qkv[idx];
            for (int ci = 0; ci < 64; ++ci) t += w_qkv[idx * 64 + ci] * b_spec[ci];
            if (idx < 64) t *= 0.25f;
            bfv[idx] = t;
        }
        return;
    }
    __shared__ __align__(16) unsigned short Bt[16 * BTP];   // [w][k''], 6.1 KB
    int d = blockIdx.x >> 4;
    int h = blockIdx.x & 15;
    int px = tid & 15, cig = tid >> 4;   // px = w, cig: 16 groups x 4 ci

    float rcur[12], rnxt[12];
    #define LOAD_CHUNK(dh_, rr)                                            \
        {                                                                  \
            int hh = h + (dh_) - 1;                                        \
            _Pragma("unroll")                                              \
            for (int cc = 0; cc < 4; ++cc) {                               \
                int ci = cig * 4 + cc;                                     \
                const float* xr = x + ci * 4096 + d * 256 + hh * 16;       \
                _Pragma("unroll")                                          \
                for (int dw = 0; dw < 3; ++dw) {                           \
                    int ww = px + dw - 1;                                  \
                    float v = 0.f;                                         \
                    if (hh >= 0 && hh <= 15 && ww >= 0 && ww <= 15)        \
                        v = xr[ww];                                        \
                    (rr)[cc * 3 + dw] = v;                                 \
                }                                                          \
            }                                                              \
        }

    LOAD_CHUNK(0, rcur);

    int wv = tid >> 6, lane = tid & 63;  // wv = Mt (co-tile 0..3)
    int quad = lane >> 4, l15 = lane & 15;
    int co = wv * 16 + l15;              // A row (m = lane&15 convention)
    float4v czero = {0.f, 0.f, 0.f, 0.f};
    float4v acc = czero;

    #pragma unroll
    for (int c = 0; c < 3; ++c) {
        __syncthreads();                 // guard Bt reuse across chunks
        #pragma unroll
        for (int cc = 0; cc < 4; ++cc) {
            int ci = cig * 4 + cc;       // k'' = dw*64 + ci (dw-major)
            Bt[px * BTP +       ci] = f2bf(rcur[cc * 3 + 0]);
            Bt[px * BTP +  64 + ci] = f2bf(rcur[cc * 3 + 1]);
            Bt[px * BTP + 128 + ci] = f2bf(rcur[cc * 3 + 2]);
        }
        __syncthreads();
        if (c < 2) LOAD_CHUNK(c + 1, rnxt);

        const unsigned short* brow = Bt + l15 * BTP + quad * 8;
        #pragma unroll
        for (int ks = 0; ks < 6; ++ks) {
            int k0 = ks * 32 + quad * 8;
            const float* wr = w_sp + co * 576 + (k0 & 63) * 9 + c * 3 + (k0 >> 6);
            short8 af;
            #pragma unroll
            for (int jj = 0; jj < 8; ++jj) af[jj] = (short)f2bf(wr[jj * 9]);
            short4v lo = *(const short4v*)(brow + ks * 32);
            short4v hi = *(const short4v*)(brow + ks * 32 + 4);
            short8 bf8 = {lo[0], lo[1], lo[2], lo[3], hi[0], hi[1], hi[2], hi[3]};
            acc = __builtin_amdgcn_mfma_f32_16x16x32_bf16(af, bf8, acc, 0, 0, 0);
        }
        #pragma unroll
        for (int q2 = 0; q2 < 12; ++q2) rcur[q2] = rnxt[q2];
    }

    int p = d * 256 + h * 16 + l15;
    #pragma unroll
    for (int r = 0; r < 4; ++r) {
        int coo = wv * 16 + quad * 4 + r;
        y1[coo * 4096 + p] = acc[r] + b_sp[coo];
    }
    #undef LOAD_CHUNK
}

// ---------------------------------------------------------------------------
// Stage 2+3: spectral-conv + QKV as MFMA GEMM (r17-verified, unchanged).
__global__ __launch_bounds__(512, 4) void qkv_mfma_kernel(
        const float* __restrict__ y1, const unsigned short* __restrict__ wfb,
        const float* __restrict__ bfv,
        unsigned short* __restrict__ qb, unsigned short* __restrict__ kb,
        unsigned short* __restrict__ vtb) {
    __shared__ __align__(16) unsigned short Bt[32 * BTP];    // [pos][k], 12.25 KB
    int bI  = blockIdx.x;            // 384 = 16 d x 8 pq x 3 ocg
    int ocg = bI % 3;                // 0=q 1=k 2=v
    int pq  = (bI / 3) & 7;
    int d   = bI / 24;
    int tid = threadIdx.x;

    {   // stage im2col slab: Bt[px][ci*3+t] = y1[ci][d+t-1][pq*32+px]
        int px  = tid & 31;
        int cig = tid >> 5;          // 0..15 (4 ci each)
        const float* yb = y1 + d * 256 + pq * 32 + px;
        #pragma unroll
        for (int cc = 0; cc < 4; ++cc) {
            int ci = cig * 4 + cc;
            const float* yc = yb + ci * 4096;
            #pragma unroll
            for (int t = 0; t < 3; ++t) {
                float v = 0.f;
                if (!((d == 0 && t == 0) || (d == 15 && t == 2)))
                    v = yc[(t - 1) * 256];
                Bt[px * BTP + ci * 3 + t] = f2bf(v);
            }
        }
    }

    int wv = tid >> 6, lane = tid & 63;
    int quad = lane >> 4, l15 = lane & 15;
    int Mt = wv >> 1;                // 0..3 (= head)
    int nt = wv & 1;                 // N-tile (16 pos)

    short8 af[6];
    {
        const unsigned short* ab = wfb + (ocg * 64 + Mt * 16 + l15) * 192 + quad * 8;
        #pragma unroll
        for (int ks = 0; ks < 6; ++ks) af[ks] = *(const short8*)(ab + ks * 32);
    }
    float bias[4];
    #pragma unroll
    for (int r = 0; r < 4; ++r) bias[r] = bfv[ocg * 64 + Mt * 16 + quad * 4 + r];

    __syncthreads();

    float4v czero = {0.f, 0.f, 0.f, 0.f};
    float4v acc = czero;
    {
        const unsigned short* brow = Bt + (nt * 16 + l15) * BTP + quad * 8;
        #pragma unroll
        for (int ks = 0; ks < 6; ++ks) {
            short4v lo = *(const short4v*)(brow + ks * 32);
            short4v hi = *(const short4v*)(brow + ks * 32 + 4);
            short8 bf8 = {lo[0], lo[1], lo[2], lo[3], hi[0], hi[1], hi[2], hi[3]};
            acc = __builtin_amdgcn_mfma_f32_16x16x32_bf16(af[ks], bf8, acc, 0, 0, 0);
        }
    }

    {   // epilogue: C row = oc_local (quad*4+r), col = pos (l15)
        int p = d * 256 + pq * 32 + nt * 16 + l15;
        if (ocg == 2) {
            int h = (p >> 4) & 15, w0 = p & 15;
            int kap = 8 * (w0 >> 2) + 4 * (h & 1) + (w0 & 3);
            unsigned short* dst = vtb + ((Mt * 16 + d) * 8 + (h >> 1)) * 512
                                      + (quad * 4) * 32 + kap;
            #pragma unroll
            for (int r = 0; r < 4; ++r) dst[r * 32] = f2bf(acc[r] + bias[r]);
        } else {
            unsigned short* dst = (ocg == 0 ? qb : kb) + Mt * 65536 + p * 16 + quad * 4;
            unsigned t0 = (unsigned)f2bf(acc[0] + bias[0])
                        | ((unsigned)f2bf(acc[1] + bias[1]) << 16);
            unsigned t1 = (unsigned)f2bf(acc[2] + bias[2])
                        | ((unsigned)f2bf(acc[3] + bias[3]) << 16);
            *(unsigned*)dst = t0;
            *(unsigned*)(dst + 2) = t1;
        }
    }
}

// ---------------------------------------------------------------------------
// Stage 4+5: retention attention via MFMA, m-pair split, WITH FUSED PROJECTION.
// After O (16 pos x 16 dims, one head) is computed, each wave projects it:
//   pout[oc][p] = sum_dim Wp[oc][head*16+dim] * O[dim][p]
// (4 MFMAs, A = W_proj head-slice, B = O via wave-private LDS round-trip)
// and atomically accumulates into out (zero-initialized by hipMemsetAsync).
// Bias added exactly once by the (head==0, mg==0) blocks.
__global__ __launch_bounds__(512, 4) void attn_proj_kernel(
        const unsigned short* __restrict__ qb, const unsigned short* __restrict__ kb,
        const unsigned short* __restrict__ vtb, const float* __restrict__ gamma,
        const float* __restrict__ w_proj, const float* __restrict__ b_proj,
        float* __restrict__ out) {
    __shared__ __align__(16) unsigned short ksh[2][4096];   // [n][o][d16], 16 KB
    __shared__ __align__(16) unsigned short vsh[2][4096];   // [np][dim][kap], 16 KB
    __shared__ __align__(16) unsigned short osh_all[8 * 16 * 24];  // 6 KB
    __shared__ float gp[32];
    int tid = threadIdx.x;
    int bI = blockIdx.x;
    int head = bI >> 8;                 // 4
    int mg   = (bI >> 5) & 7;           // 8 m-pairs
    int oct  = bI & 31;                 // 32 q-octets per head

    if (tid < 32) {
        float g = 1.f / (1.f + __expf(-gamma[0]));
        gp[tid] = __powf(g, (float)tid);
    }

    int wv = tid >> 6, lane = tid & 63;
    int quad = lane >> 4, l15 = lane & 15;
    int t = oct * 8 + wv;               // tile index (= i*16 + j)
    int i = t >> 4, j = t & 15;

    short8 zero8 = {0, 0, 0, 0, 0, 0, 0, 0};
    float4v czero = {0.f, 0.f, 0.f, 0.f};
    short8 qf = zero8;
    if (quad < 2)
        qf = *(const short8*)(qb + head * 65536 + (t * 16 + l15) * 16 + quad * 8);

    // stage BOTH slabs of the m-pair at once (no serial chain)
    const unsigned short* kbh = kb  + head * 65536 + mg * 2 * 4096;
    const unsigned short* vbh = vtb + head * 65536 + mg * 2 * 4096;
    float4 k0 = ((const float4*)kbh)[tid];
    float4 v0 = ((const float4*)vbh)[tid];
    float4 k1 = ((const float4*)(kbh + 4096))[tid];
    float4 v1 = ((const float4*)(vbh + 4096))[tid];
    ((float4*)ksh[0])[tid] = k0;
    ((float4*)vsh[0])[tid] = v0;
    ((float4*)ksh[1])[tid] = k1;
    ((float4*)vsh[1])[tid] = v1;
    __syncthreads();                    // gp + both slabs ready

    float wd[4];
    #pragma unroll
    for (int r = 0; r < 4; ++r)
        wd[r] = gp[abs(l15 - (quad * 4 + r))] * 1.4426950408889634f;   // log2e

    float4v O = czero;
    #pragma unroll
    for (int mm = 0; mm < 2; ++mm) {
        int m = mg * 2 + mm;
        const unsigned short* kk = ksh[mm];
        const unsigned short* vv = vsh[mm];
        int eim = abs(i - m);
        #pragma unroll
        for (int np = 0; np < 8; ++np) {
            union { unsigned u[4]; short8 s8; } a2u;
            #pragma unroll
            for (int s = 0; s < 2; ++s) {
                int n = np * 2 + s;
                short8 a1 = zero8;
                if (quad < 2)
                    a1 = *(const short8*)(kk + n * 256 + l15 * 16 + quad * 8);
                float4v d1 = __builtin_amdgcn_mfma_f32_16x16x32_bf16(a1, qf, czero, 0, 0, 0);
                float smn = gp[eim + abs(j - n)];        // wave-uniform broadcast
                float e0 = __builtin_amdgcn_exp2f(d1[0] * smn * wd[0]);
                float e1 = __builtin_amdgcn_exp2f(d1[1] * smn * wd[1]);
                float e2 = __builtin_amdgcn_exp2f(d1[2] * smn * wd[2]);
                float e3 = __builtin_amdgcn_exp2f(d1[3] * smn * wd[3]);
                float sm = e0 + e1 + e2 + e3;
                sm += __shfl_xor(sm, 16);
                sm += __shfl_xor(sm, 32);
                float inv = __builtin_amdgcn_rcpf(sm);
                union { float f; unsigned u; } p0, p1, p2, p3;
                p0.f = e0 * inv; p1.f = e1 * inv;
                p2.f = e2 * inv; p3.f = e3 * inv;
                // round-half pack via v_perm (3 ops/pair)
                a2u.u[s * 2]     = __builtin_amdgcn_perm(p1.u + 0x8000u, p0.u + 0x8000u, 0x07060302u);
                a2u.u[s * 2 + 1] = __builtin_amdgcn_perm(p3.u + 0x8000u, p2.u + 0x8000u, 0x07060302u);
            }
            short8 b2 = *(const short8*)(vv + np * 512 + l15 * 32 + quad * 8);
            O = __builtin_amdgcn_mfma_f32_16x16x32_bf16(a2u.s8, b2, O, 0, 0, 0);
        }
    }

    // ---- fused projection epilogue -------------------------------------
    // O C-layout: col=l15=dim, row=quad*4+r=qw. Stage to wave-private LDS as
    // osh[qw][dim] (row stride 24 shorts, 16B-aligned rows).
    unsigned short* osh = osh_all + wv * 384;
    #pragma unroll
    for (int r = 0; r < 4; ++r)
        osh[(quad * 4 + r) * 24 + l15] = f2bf(O[r]);
    // B fragment: lane n=l15=qw, k=quad*8+j = dim (quad<2; upper half zero)
    short8 b_o = zero8;
    if (quad < 2)
        b_o = *(const short8*)(osh + l15 * 24 + quad * 8);

    bool addb = (head == 0) && (mg == 0);
    #pragma unroll
    for (int Mt2 = 0; Mt2 < 4; ++Mt2) {
        short8 a_wp = zero8;
        if (quad < 2) {
            const float* wr = w_proj + (Mt2 * 16 + l15) * 64 + head * 16 + quad * 8;
            float4 wa = *(const float4*)wr;
            float4 wb = *(const float4*)(wr + 4);
            a_wp[0] = (short)f2bf(wa.x); a_wp[1] = (short)f2bf(wa.y);
            a_wp[2] = (short)f2bf(wa.z); a_wp[3] = (short)f2bf(wa.w);
            a_wp[4] = (short)f2bf(wb.x); a_wp[5] = (short)f2bf(wb.y);
            a_wp[6] = (short)f2bf(wb.z); a_wp[7] = (short)f2bf(wb.w);
        }
        float4v accp = __builtin_amdgcn_mfma_f32_16x16x32_bf16(a_wp, b_o, czero, 0, 0, 0);
        // C: col=l15 = position-in-tile, row=quad*4+r = oc_local
        #pragma unroll
        for (int r = 0; r < 4; ++r) {
            int oc = Mt2 * 16 + quad * 4 + r;
            float val = accp[r];
            if (addb) val += b_proj[oc];
            atomicAdd(out + oc * 4096 + t * 16 + l15, val);
        }
    }
}

// ---------------------------------------------------------------------------
extern "C" void kernel_launch(void* const* d_in, const int* in_sizes, int n_in,
                              void* d_out, int out_size, void* d_ws, size_t ws_size,
                              hipStream_t stream) {
    const float* x      = (const float*)d_in[0];
    const float* gamma  = (const float*)d_in[1];
    const float* w_sp   = (const float*)d_in[2];
    const float* b_sp   = (const float*)d_in[3];
    const float* w_spec = (const float*)d_in[4];
    const float* b_spec = (const float*)d_in[5];
    const float* w_qkv  = (const float*)d_in[6];
    const float* b_qkv  = (const float*)d_in[7];
    const float* w_proj = (const float*)d_in[8];
    const float* b_proj = (const float*)d_in[9];
    float* out = (float*)d_out;

    float* ws = (float*)d_ws;
    float* y1  = ws;                         // [64][4096] f32
    unsigned short* wfb = (unsigned short*)(ws + CN);   // [192][192] bf16
    float* bfv = ws + CN + 20480;            // [192] fused bias f32
    unsigned short* qb  = (unsigned short*)(ws + 2 * CN);            // 512 KB bf16
    unsigned short* kb  = (unsigned short*)(ws + 2 * CN + CN / 2);   // 512 KB bf16
    unsigned short* vtb = (unsigned short*)(ws + 3 * CN);            // 512 KB bf16

    hipMemsetAsync(out, 0, (size_t)out_size * sizeof(float), stream);
    conv_sp_wfuse_kernel<<< 400, 256, 0, stream>>>(x, w_sp, b_sp, y1,
                                                   w_spec, b_spec, w_qkv, b_qkv,
                                                   wfb, bfv);
    qkv_mfma_kernel     <<< 384, 512, 0, stream>>>(y1, wfb, bfv, qb, kb, vtb);
    attn_proj_kernel    <<<1024, 512, 0, stream>>>(qb, kb, vtb, gamma,
                                                   w_proj, b_proj, out);
}

// Round 19
// 117.811 us; speedup vs baseline: 1.0703x; 1.0703x over previous
//
#include <hip/hip_runtime.h>
#include <math.h>

// Problem constants: B=1, C=64, D=H=W=16, HEADS=4, HD=16
#define CN   262144        // C * 4096 floats per [C, D, H, W] tensor
#define BTP 196            // qkv/conv Bt row stride in bf16
#define PTP 68             // proj Bt row stride in bf16

typedef __attribute__((ext_vector_type(8))) short short8;   // 8 bf16 (4 VGPRs)
typedef __attribute__((ext_vector_type(4))) short short4v;  // 8 B
typedef __attribute__((ext_vector_type(4))) float float4v;  // MFMA C/D

static __device__ __forceinline__ unsigned short f2bf(float f) {
    union { float f; unsigned u; } v; v.f = f;
    unsigned r = (v.u + 0x7FFFu + ((v.u >> 16) & 1u)) >> 16;   // RNE
    return (unsigned short)r;
}

// ---------------------------------------------------------------------------
// Stage 0: weight prep. idx<36864: wsb[dh][co][ci*3+dw] bf16 (spatial conv A).
// idx>=36864: wfuse — conv_spec folded into qkv weights (exact), wfb/bfv.
// 144 blocks x 512 thr.   (r16-verified)
__global__ __launch_bounds__(512) void wprep_kernel(
        const float* __restrict__ w_sp,
        const float* __restrict__ w_spec, const float* __restrict__ b_spec,
        const float* __restrict__ w_qkv, const float* __restrict__ b_qkv,
        unsigned short* __restrict__ wsb,
        unsigned short* __restrict__ wfb, float* __restrict__ bfv) {
    int idx = blockIdx.x * 512 + threadIdx.x;    // 0..73727
    if (idx < 36864) {
        int dh  = idx / 12288;
        int rem = idx % 12288;
        int co  = rem / 192;
        int kp  = rem % 192;                     // = ci*3 + dw
        int ci = kp / 3, dw = kp % 3;
        wsb[idx] = f2bf(w_sp[co * 576 + ci * 9 + dh * 3 + dw]);
    } else {
        int j = idx - 36864;                     // 0..36863
        int oc = j / 192;
        int r  = j % 192;                        // = cj*3 + t
        float s = 0.f;
        #pragma unroll 8
        for (int ci = 0; ci < 64; ++ci)
            s += w_qkv[oc * 64 + ci] * w_spec[ci * 192 + r];
        if (oc < 64) s *= 0.25f;
        wfb[oc * 192 + r] = f2bf(s);
        if (j < 192) {
            float t = b_qkv[j];
            for (int ci = 0; ci < 64; ++ci) t += w_qkv[j * 64 + ci] * b_spec[ci];
            if (j < 64) t *= 0.25f;
            bfv[j] = t;
        }
    }
}

// ---------------------------------------------------------------------------
// Stage 1: spatial conv 3x3 as MFMA GEMM. Block = (d, h): 256 blocks x 256
// thr. M=64 co, N=16 w, K=576 streamed as 3 dh-chunks of 192 (k'=ci*3+dw).
// (r16-verified)
__global__ __launch_bounds__(256, 4) void conv_sp_mfma_kernel(
        const float* __restrict__ x, const unsigned short* __restrict__ wsb,
        const float* __restrict__ b_sp, float* __restrict__ y1) {
    __shared__ __align__(16) unsigned short Bt[16 * BTP];   // [w][k'], 6.1 KB
    int d = blockIdx.x >> 4;
    int h = blockIdx.x & 15;
    int tid = threadIdx.x;               // 256
    int px = tid & 15, cig = tid >> 4;   // px = w, cig: 16 groups x 4 ci

    float rcur[12], rnxt[12];
    // load chunk dh: rr[cc*3+dw] = x[ci][d][h+dh-1][px+dw-1] (0 if OOB)
    #define LOAD_CHUNK(dh_, rr)                                            \
        {                                                                  \
            int hh = h + (dh_) - 1;                                        \
            _Pragma("unroll")                                              \
            for (int cc = 0; cc < 4; ++cc) {                               \
                int ci = cig * 4 + cc;                                     \
                const float* xr = x + ci * 4096 + d * 256 + hh * 16;       \
                _Pragma("unroll")                                          \
                for (int dw = 0; dw < 3; ++dw) {                           \
                    int ww = px + dw - 1;                                  \
                    float v = 0.f;                                         \
                    if (hh >= 0 && hh <= 15 && ww >= 0 && ww <= 15)        \
                        v = xr[ww];                                        \
                    (rr)[cc * 3 + dw] = v;                                 \
                }                                                          \
            }                                                              \
        }

    LOAD_CHUNK(0, rcur);

    int wv = tid >> 6, lane = tid & 63;  // wv = Mt (co-tile 0..3)
    int quad = lane >> 4, l15 = lane & 15;
    float4v czero = {0.f, 0.f, 0.f, 0.f};
    float4v acc = czero;

    #pragma unroll
    for (int c = 0; c < 3; ++c) {
        __syncthreads();                 // guard Bt reuse across chunks
        #pragma unroll
        for (int cc = 0; cc < 4; ++cc) {
            int ci = cig * 4 + cc;
            Bt[px * BTP + ci * 3 + 0] = f2bf(rcur[cc * 3 + 0]);
            Bt[px * BTP + ci * 3 + 1] = f2bf(rcur[cc * 3 + 1]);
            Bt[px * BTP + ci * 3 + 2] = f2bf(rcur[cc * 3 + 2]);
        }
        __syncthreads();
        if (c < 2) LOAD_CHUNK(c + 1, rnxt);

        const unsigned short* ab = wsb + c * 12288 + (wv * 16 + l15) * 192 + quad * 8;
        const unsigned short* brow = Bt + l15 * BTP + quad * 8;
        #pragma unroll
        for (int ks = 0; ks < 6; ++ks) {
            short8 af = *(const short8*)(ab + ks * 32);
            short4v lo = *(const short4v*)(brow + ks * 32);
            short4v hi = *(const short4v*)(brow + ks * 32 + 4);
            short8 bf8 = {lo[0], lo[1], lo[2], lo[3], hi[0], hi[1], hi[2], hi[3]};
            acc = __builtin_amdgcn_mfma_f32_16x16x32_bf16(af, bf8, acc, 0, 0, 0);
        }
        #pragma unroll
        for (int q2 = 0; q2 < 12; ++q2) rcur[q2] = rnxt[q2];
    }

    // epilogue: C row = co_local (quad*4+r), col = w (l15)
    int p = d * 256 + h * 16 + l15;
    #pragma unroll
    for (int r = 0; r < 4; ++r) {
        int co = wv * 16 + quad * 4 + r;
        y1[co * 4096 + p] = acc[r] + b_sp[co];
    }
    #undef LOAD_CHUNK
}

// ---------------------------------------------------------------------------
// Stage 2+3: spectral-conv + QKV as MFMA GEMM (r16-verified).
// Block = (d, pos-eighth, oc-third): 384 blocks. M=64, N=32, K=192.
__global__ __launch_bounds__(512, 4) void qkv_mfma_kernel(
        const float* __restrict__ y1, const unsigned short* __restrict__ wfb,
        const float* __restrict__ bfv,
        unsigned short* __restrict__ qb, unsigned short* __restrict__ kb,
        unsigned short* __restrict__ vtb) {
    __shared__ __align__(16) unsigned short Bt[32 * BTP];    // [pos][k], 12.25 KB
    int bI  = blockIdx.x;            // 384 = 16 d x 8 pq x 3 ocg
    int ocg = bI % 3;                // 0=q 1=k 2=v
    int pq  = (bI / 3) & 7;
    int d   = bI / 24;
    int tid = threadIdx.x;

    {   // stage im2col slab: Bt[px][ci*3+t] = y1[ci][d+t-1][pq*32+px]
        int px  = tid & 31;
        int cig = tid >> 5;          // 0..15 (4 ci each)
        const float* yb = y1 + d * 256 + pq * 32 + px;
        #pragma unroll
        for (int cc = 0; cc < 4; ++cc) {
            int ci = cig * 4 + cc;
            const float* yc = yb + ci * 4096;
            #pragma unroll
            for (int t = 0; t < 3; ++t) {
                float v = 0.f;
                if (!((d == 0 && t == 0) || (d == 15 && t == 2)))
                    v = yc[(t - 1) * 256];
                Bt[px * BTP + ci * 3 + t] = f2bf(v);
            }
        }
    }

    int wv = tid >> 6, lane = tid & 63;
    int quad = lane >> 4, l15 = lane & 15;
    int Mt = wv >> 1;                // 0..3 (= head)
    int nt = wv & 1;                 // N-tile (16 pos)

    short8 af[6];
    {
        const unsigned short* ab = wfb + (ocg * 64 + Mt * 16 + l15) * 192 + quad * 8;
        #pragma unroll
        for (int ks = 0; ks < 6; ++ks) af[ks] = *(const short8*)(ab + ks * 32);
    }
    float bias[4];
    #pragma unroll
    for (int r = 0; r < 4; ++r) bias[r] = bfv[ocg * 64 + Mt * 16 + quad * 4 + r];

    __syncthreads();

    float4v czero = {0.f, 0.f, 0.f, 0.f};
    float4v acc = czero;
    {
        const unsigned short* brow = Bt + (nt * 16 + l15) * BTP + quad * 8;
        #pragma unroll
        for (int ks = 0; ks < 6; ++ks) {
            short4v lo = *(const short4v*)(brow + ks * 32);
            short4v hi = *(const short4v*)(brow + ks * 32 + 4);
            short8 bf8 = {lo[0], lo[1], lo[2], lo[3], hi[0], hi[1], hi[2], hi[3]};
            acc = __builtin_amdgcn_mfma_f32_16x16x32_bf16(af[ks], bf8, acc, 0, 0, 0);
        }
    }

    {   // epilogue: C row = oc_local (quad*4+r), col = pos (l15)
        int p = d * 256 + pq * 32 + nt * 16 + l15;
        if (ocg == 2) {
            int h = (p >> 4) & 15, w0 = p & 15;
            int kap = 8 * (w0 >> 2) + 4 * (h & 1) + (w0 & 3);
            unsigned short* dst = vtb + ((Mt * 16 + d) * 8 + (h >> 1)) * 512
                                      + (quad * 4) * 32 + kap;
            #pragma unroll
            for (int r = 0; r < 4; ++r) dst[r * 32] = f2bf(acc[r] + bias[r]);
        } else {
            unsigned short* dst = (ocg == 0 ? qb : kb) + Mt * 65536 + p * 16 + quad * 4;
            unsigned t0 = (unsigned)f2bf(acc[0] + bias[0])
                        | ((unsigned)f2bf(acc[1] + bias[1]) << 16);
            unsigned t1 = (unsigned)f2bf(acc[2] + bias[2])
                        | ((unsigned)f2bf(acc[3] + bias[3]) << 16);
            *(unsigned*)dst = t0;
            *(unsigned*)(dst + 2) = t1;
        }
    }
}

// ---------------------------------------------------------------------------
// Stage 4: retention attention via MFMA, m-pair split (r16-verified).
__global__ __launch_bounds__(512, 4) void attn_kernel(
        const unsigned short* __restrict__ qb, const unsigned short* __restrict__ kb,
        const unsigned short* __restrict__ vtb, const float* __restrict__ gamma,
        float* __restrict__ aoall) {
    __shared__ __align__(16) unsigned short ksh[2][4096];   // [n][o][d16], 16 KB
    __shared__ __align__(16) unsigned short vsh[2][4096];   // [np][dim][kap], 16 KB
    __shared__ float gp[32];
    int tid = threadIdx.x;
    int bI = blockIdx.x;
    int head = bI >> 8;                 // 4
    int mg   = (bI >> 5) & 7;           // 8 m-pairs
    int oct  = bI & 31;                 // 32 q-octets per head

    if (tid < 32) {
        float g = 1.f / (1.f + __expf(-gamma[0]));
        gp[tid] = __powf(g, (float)tid);
    }

    int wv = tid >> 6, lane = tid & 63;
    int quad = lane >> 4, l15 = lane & 15;
    int t = oct * 8 + wv;               // tile index (= i*16 + j)
    int i = t >> 4, j = t & 15;

    short8 zero8 = {0, 0, 0, 0, 0, 0, 0, 0};
    float4v czero = {0.f, 0.f, 0.f, 0.f};
    short8 qf = zero8;
    if (quad < 2)
        qf = *(const short8*)(qb + head * 65536 + (t * 16 + l15) * 16 + quad * 8);

    // stage BOTH slabs of the m-pair at once (no serial chain)
    const unsigned short* kbh = kb  + head * 65536 + mg * 2 * 4096;
    const unsigned short* vbh = vtb + head * 65536 + mg * 2 * 4096;
    float4 k0 = ((const float4*)kbh)[tid];
    float4 v0 = ((const float4*)vbh)[tid];
    float4 k1 = ((const float4*)(kbh + 4096))[tid];
    float4 v1 = ((const float4*)(vbh + 4096))[tid];
    ((float4*)ksh[0])[tid] = k0;
    ((float4*)vsh[0])[tid] = v0;
    ((float4*)ksh[1])[tid] = k1;
    ((float4*)vsh[1])[tid] = v1;
    __syncthreads();                    // gp + both slabs ready

    float wd[4];
    #pragma unroll
    for (int r = 0; r < 4; ++r)
        wd[r] = gp[abs(l15 - (quad * 4 + r))] * 1.4426950408889634f;   // log2e

    float4v O = czero;
    #pragma unroll
    for (int mm = 0; mm < 2; ++mm) {
        int m = mg * 2 + mm;
        const unsigned short* kk = ksh[mm];
        const unsigned short* vv = vsh[mm];
        int eim = abs(i - m);
        #pragma unroll
        for (int np = 0; np < 8; ++np) {
            union { unsigned u[4]; short8 s8; } a2u;
            #pragma unroll
            for (int s = 0; s < 2; ++s) {
                int n = np * 2 + s;
                short8 a1 = zero8;
                if (quad < 2)
                    a1 = *(const short8*)(kk + n * 256 + l15 * 16 + quad * 8);
                float4v d1 = __builtin_amdgcn_mfma_f32_16x16x32_bf16(a1, qf, czero, 0, 0, 0);
                float smn = gp[eim + abs(j - n)];        // wave-uniform broadcast
                float e0 = __builtin_amdgcn_exp2f(d1[0] * smn * wd[0]);
                float e1 = __builtin_amdgcn_exp2f(d1[1] * smn * wd[1]);
                float e2 = __builtin_amdgcn_exp2f(d1[2] * smn * wd[2]);
                float e3 = __builtin_amdgcn_exp2f(d1[3] * smn * wd[3]);
                float sm = e0 + e1 + e2 + e3;
                sm += __shfl_xor(sm, 16);
                sm += __shfl_xor(sm, 32);
                float inv = __builtin_amdgcn_rcpf(sm);
                union { float f; unsigned u; } p0, p1, p2, p3;
                p0.f = e0 * inv; p1.f = e1 * inv;
                p2.f = e2 * inv; p3.f = e3 * inv;
                a2u.u[s * 2]     = ((p0.u + 0x8000u) >> 16) | ((p1.u + 0x8000u) & 0xFFFF0000u);
                a2u.u[s * 2 + 1] = ((p2.u + 0x8000u) >> 16) | ((p3.u + 0x8000u) & 0xFFFF0000u);
            }
            short8 b2 = *(const short8*)(vv + np * 512 + l15 * 32 + quad * 8);
            O = __builtin_amdgcn_mfma_f32_16x16x32_bf16(a2u.s8, b2, O, 0, 0, 0);
        }
    }

    float* aop = aoall + mg * CN;
    float4 ov = {O[0], O[1], O[2], O[3]};
    *(float4*)(aop + (head * 16 + l15) * 4096 + t * 16 + quad * 4) = ov;
}

// ---------------------------------------------------------------------------
// Stage 5: projection as MFMA GEMM (r16-verified).
__global__ __launch_bounds__(256, 8) void proj_mfma_kernel(
        const float* __restrict__ aoall,
        const float* __restrict__ w, const float* __restrict__ b,
        float* __restrict__ out) {
    __shared__ __align__(16) unsigned short Bt[16 * PTP];    // [pos][ci], 2.2 KB
    int d   = blockIdx.x >> 4;
    int p16 = blockIdx.x & 15;
    int tid = threadIdx.x;               // 256

    {   // stage: sum 8 partials -> bf16 Bt[px][ci]
        int px = tid & 15, cig = tid >> 4;        // cig 0..15 (4 ci each)
        int gbase = d * 256 + p16 * 16 + px;
        #pragma unroll
        for (int cc = 0; cc < 4; ++cc) {
            int ci = cig * 4 + cc;
            int ga = ci * 4096 + gbase;
            float v = 0.f;
            #pragma unroll
            for (int k = 0; k < 8; ++k) v += aoall[k * CN + ga];
            Bt[px * PTP + ci] = f2bf(v);
        }
    }
    __syncthreads();

    int wv = tid >> 6, lane = tid & 63;  // 4 waves: wv = M-tile
    int quad = lane >> 4, l15 = lane & 15;
    float4v czero = {0.f, 0.f, 0.f, 0.f};
    float4v acc = czero;

    short8 af[2];
    const float* wsrc = w + (wv * 16 + l15) * 64 + quad * 8;
    #pragma unroll
    for (int ks = 0; ks < 2; ++ks) {
        float4 wa = *(const float4*)(wsrc + ks * 32);
        float4 wb = *(const float4*)(wsrc + ks * 32 + 4);
        short8 a8 = {(short)f2bf(wa.x), (short)f2bf(wa.y), (short)f2bf(wa.z),
                     (short)f2bf(wa.w), (short)f2bf(wb.x), (short)f2bf(wb.y),
                     (short)f2bf(wb.z), (short)f2bf(wb.w)};
        af[ks] = a8;
    }
    const unsigned short* brow = Bt + l15 * PTP + quad * 8;
    #pragma unroll
    for (int ks = 0; ks < 2; ++ks) {
        short4v lo = *(const short4v*)(brow + ks * 32);
        short4v hi = *(const short4v*)(brow + ks * 32 + 4);
        short8 bf8 = {lo[0], lo[1], lo[2], lo[3], hi[0], hi[1], hi[2], hi[3]};
        acc = __builtin_amdgcn_mfma_f32_16x16x32_bf16(af[ks], bf8, acc, 0, 0, 0);
    }

    int p = d * 256 + p16 * 16 + l15;
    #pragma unroll
    for (int r = 0; r < 4; ++r) {
        int oc = wv * 16 + quad * 4 + r;
        out[oc * 4096 + p] = acc[r] + b[oc];
    }
}

// ---------------------------------------------------------------------------
extern "C" void kernel_launch(void* const* d_in, const int* in_sizes, int n_in,
                              void* d_out, int out_size, void* d_ws, size_t ws_size,
                              hipStream_t stream) {
    const float* x      = (const float*)d_in[0];
    const float* gamma  = (const float*)d_in[1];
    const float* w_sp   = (const float*)d_in[2];
    const float* b_sp   = (const float*)d_in[3];
    const float* w_spec = (const float*)d_in[4];
    const float* b_spec = (const float*)d_in[5];
    const float* w_qkv  = (const float*)d_in[6];
    const float* b_qkv  = (const float*)d_in[7];
    const float* w_proj = (const float*)d_in[8];
    const float* b_proj = (const float*)d_in[9];
    float* out = (float*)d_out;

    float* ws = (float*)d_ws;
    float* y1  = ws;                         // [64][4096] f32
    unsigned short* wfb = (unsigned short*)(ws + CN);   // [192][192] bf16
    float* bfv = ws + CN + 20480;            // [192] fused bias f32
    unsigned short* wsb = (unsigned short*)(ws + CN + 24576);  // [3][64][192] bf16
    unsigned short* qb  = (unsigned short*)(ws + 2 * CN);            // 512 KB bf16
    unsigned short* kb  = (unsigned short*)(ws + 2 * CN + CN / 2);   // 512 KB bf16
    unsigned short* vtb = (unsigned short*)(ws + 3 * CN);            // 512 KB bf16
    float* aoall = ws + 3 * CN + CN / 2;     // 8 x [64][4096] m-pair partials

    wprep_kernel       <<< 144, 512, 0, stream>>>(w_sp, w_spec, b_spec,
                                                  w_qkv, b_qkv, wsb, wfb, bfv);
    conv_sp_mfma_kernel<<< 256, 256, 0, stream>>>(x, wsb, b_sp, y1);
    qkv_mfma_kernel    <<< 384, 512, 0, stream>>>(y1, wfb, bfv, qb, kb, vtb);
    attn_kernel        <<<1024, 512, 0, stream>>>(qb, kb, vtb, gamma, aoall);
    proj_mfma_kernel   <<< 256, 256, 0, stream>>>(aoall, w_proj, b_proj, out);
}